// Round 12
// baseline (311.070 us; speedup 1.0000x reference)
//
#include <hip/hip_runtime.h>
#include <math.h>

// Problem constants (fixed by reference setup_inputs)
constexpr int B = 32;
constexpr int P = 1024;
constexpr int S = 1023;          // segments per lane
constexpr float EPS = 1e-8f;

#define INV8PI 0.039788735772973836  // 1/(8*pi)
#define INV2PI 0.15915494309189535   // 1/(2*pi)  (= 2*alpha/(4*pi), sign folded)

typedef float f32x4 __attribute__((ext_vector_type(4)));

// seg = {dlx, dly, midx, midy}, faithful to reference:
// diff = p[i+1]-p[i]; scale = sqrt(s2)/sqrt(s2+eps); dl = diff*scale; mid = avg
__device__ __forceinline__ float4 make_seg(const float2* __restrict__ pts, int i) {
    float2 a = pts[i];
    float2 b = pts[i + 1];
    float dx = b.x - a.x, dy = b.y - a.y;
    float s2 = dx * dx + dy * dy;
    float scale = sqrtf(s2) / sqrtf(s2 + EPS);
    float4 r;
    r.x = dx * scale;
    r.y = dy * scale;
    r.z = 0.5f * (a.x + b.x);
    r.w = 0.5f * (a.y + b.y);
    return r;
}

// grid (72, 256) x 256 threads. blockIdx.y = problem lane; strip s = 4*blockIdx.x + wave.
// 288 strips/lane (256 rows x 32 cols each): PP-tri 80 (cs>=8rb), GG-tri 80, PG 128.
// One strip per wave -> 73728 waves = 72/SIMD (divisible by 8/4/2: no tail).
// Wave stages its own 32-col panel in LDS; each thread owns 4 rows (global reads).
__global__ __launch_bounds__(256, 8) void
pair_kernel(const float* __restrict__ pred, const float* __restrict__ gt,
            double* __restrict__ acc) {
    __shared__ __align__(16) float pan[4][4][32];  // [wave][dlx,dly,mx,my][col], 2 KB
    __shared__ double wsum[4];

    const int plane = blockIdx.y;
    const int tid   = threadIdx.x;
    const int wv    = tid >> 6;
    const int l     = tid & 63;
    const int s     = blockIdx.x * 4 + wv;   // 0..287

    // decode strip -> (mt, rb, cs)
    int mt, rb, cs;
    if (s < 160) {
        mt = (s < 80) ? 0 : 1;               // 0: pred-pred, 1: gt-gt
        const int u = (s < 80) ? s : s - 80;
        if      (u < 32) { rb = 0; cs = u; }
        else if (u < 56) { rb = 1; cs = u - 32 + 8; }
        else if (u < 72) { rb = 2; cs = u - 56 + 16; }
        else             { rb = 3; cs = u - 72 + 24; }
    } else {
        mt = 2;                              // pred-gt
        const int u = s - 160;
        rb = u >> 5; cs = u & 31;
    }

    const float2* rowpts = (const float2*)(mt == 1 ? gt : pred) + (size_t)plane * P;
    const float2* colpts = (const float2*)(mt == 0 ? pred : gt) + (size_t)plane * P;

    double accd = 0.0;

    // stage this wave's 32 column segments (lanes 0..31, stride-1: conflict-free).
    // Line term folded in: PP/GG rb==0 strips stage each pred/gt seg exactly once
    // across the whole grid -> add |dl|/(8pi) here.
    if (l < 32) {
        const int j = cs * 32 + l;
        float4 sg = {0.f, 0.f, 0.f, 0.f};    // zero pad (j==S): contributes exactly 0
        if (j < S) sg = make_seg(colpts, j);
        pan[wv][0][l] = sg.x; pan[wv][1][l] = sg.y;
        pan[wv][2][l] = sg.z; pan[wv][3][l] = sg.w;
        if (mt < 2 && rb == 0)
            accd += (double)sqrtf(sg.x * sg.x + sg.y * sg.y) * INV8PI;
    }

    // this thread's 4 row segments (rows rb*256 + 4l + k), read from global (L2-hot)
    const int i0 = rb * 256 + 4 * l;
    float rx[4], ry[4], ru[4], rv[4];
#pragma unroll
    for (int k = 0; k < 4; ++k) {
        float4 r = {0.f, 0.f, 0.f, 0.f};     // row >= S: zero -> contributes 0
        if (i0 + k < S) r = make_seg(rowpts, i0 + k);
        rx[k] = r.x; ry[k] = r.y; ru[k] = r.z; rv[k] = r.w;
    }
    __syncthreads();

    const f32x4* qx = (const f32x4*)pan[wv][0];
    const f32x4* qy = (const f32x4*)pan[wv][1];
    const f32x4* qu = (const f32x4*)pan[wv][2];
    const f32x4* qv = (const f32x4*)pan[wv][3];

    f32x4 a[4] = {{0,0,0,0},{0,0,0,0},{0,0,0,0},{0,0,0,0}};
    const bool masked = (mt < 2) && ((cs >> 3) == rb);   // diagonal strip: mask j > i

    if (!masked) {
#pragma unroll
        for (int q = 0; q < 8; ++q) {
            f32x4 cx = qx[q], cy = qy[q], cu = qu[q], cv = qv[q];
#pragma unroll
            for (int k = 0; k < 4; ++k) {
                f32x4 rdx = cu - ru[k];
                f32x4 rdy = cv - rv[k];
                f32x4 d2  = rdx * rdx + (rdy * rdy + (f32x4)1e-30f);
                f32x4 dot = rx[k] * cx + ry[k] * cy;
                f32x4 rs;
                rs.x = __builtin_amdgcn_rsqf(d2.x);
                rs.y = __builtin_amdgcn_rsqf(d2.y);
                rs.z = __builtin_amdgcn_rsqf(d2.z);
                rs.w = __builtin_amdgcn_rsqf(d2.w);
                a[k] += dot * rs;
            }
        }
    } else {
#pragma unroll
        for (int q = 0; q < 8; ++q) {
            f32x4 cx = qx[q], cy = qy[q], cu = qu[q], cv = qv[q];
            const int jb = cs * 32 + 4 * q;
#pragma unroll
            for (int k = 0; k < 4; ++k) {
                f32x4 rdx = cu - ru[k];
                f32x4 rdy = cv - rv[k];
                f32x4 d2  = rdx * rdx + (rdy * rdy + (f32x4)1e-30f);
                f32x4 dot = rx[k] * cx + ry[k] * cy;
                f32x4 rs;
                rs.x = __builtin_amdgcn_rsqf(d2.x);
                rs.y = __builtin_amdgcn_rsqf(d2.y);
                rs.z = __builtin_amdgcn_rsqf(d2.z);
                rs.w = __builtin_amdgcn_rsqf(d2.w);
                f32x4 tv = dot * rs;
                const int ik = i0 + k;
                tv.x = (jb + 0 > ik) ? tv.x : 0.f;
                tv.y = (jb + 1 > ik) ? tv.y : 0.f;
                tv.z = (jb + 2 > ik) ? tv.z : 0.f;
                tv.w = (jb + 3 > ik) ? tv.w : 0.f;
                a[k] += tv;
            }
        }
    }

    // flush strip sum (each fp32 component summed only 8 terms) with its coefficient
    double su = 0.0;
#pragma unroll
    for (int k = 0; k < 4; ++k)
        su += (double)a[k].x + (double)a[k].y + (double)a[k].z + (double)a[k].w;
    accd += su * ((mt == 2) ? INV2PI : INV8PI);

    // wave reduce, cross-wave via LDS, one double atomic per block
    for (int off = 32; off; off >>= 1) accd += __shfl_down(accd, off, 64);
    if (l == 0) wsum[wv] = accd;
    __syncthreads();
    if (tid == 0)
        atomicAdd(acc, wsum[0] + wsum[1] + wsum[2] + wsum[3]);
}

__global__ void finalize_kernel(const double* __restrict__ acc, float* __restrict__ out) {
    out[0] = (float)(acc[0] / (double)B);
}

extern "C" void kernel_launch(void* const* d_in, const int* in_sizes, int n_in,
                              void* d_out, int out_size, void* d_ws, size_t ws_size,
                              hipStream_t stream) {
    const float* pred = (const float*)d_in[0];
    const float* gt   = (const float*)d_in[1];
    double* acc = (double*)d_ws;

    hipMemsetAsync(d_ws, 0, sizeof(double), stream);

    dim3 grid(72, 256);
    pair_kernel<<<grid, dim3(256), 0, stream>>>(pred, gt, acc);
    finalize_kernel<<<1, 1, 0, stream>>>(acc, (float*)d_out);
}

// Round 16
// 293.228 us; speedup vs baseline: 1.0608x; 1.0608x over previous
//
#include <hip/hip_runtime.h>
#include <math.h>

// Problem constants (fixed by reference setup_inputs)
constexpr int B = 32;
constexpr int P = 1024;
constexpr int S = 1023;          // segments per lane
constexpr float EPS = 1e-8f;

#define INV8PI 0.039788735772973836  // 1/(8*pi)
#define INV2PI 0.15915494309189535   // 1/(2*pi)  (= 2*alpha/(4*pi), sign folded)

typedef float f32x4 __attribute__((ext_vector_type(4)));

// seg = {dlx, dly, midx, midy}, faithful to reference:
// diff = p[i+1]-p[i]; scale = sqrt(s2)/sqrt(s2+eps); dl = diff*scale; mid = avg
__device__ __forceinline__ float4 make_seg(const float2* __restrict__ pts, int i) {
    float2 a = pts[i];
    float2 b = pts[i + 1];
    float dx = b.x - a.x, dy = b.y - a.y;
    float s2 = dx * dx + dy * dy;
    float scale = sqrtf(s2) / sqrtf(s2 + EPS);
    float4 r;
    r.x = dx * scale;
    r.y = dy * scale;
    r.z = 0.5f * (a.x + b.x);
    r.w = 0.5f * (a.y + b.y);
    return r;
}

// grid (72, 256) x 256 threads. blockIdx.y = problem lane; strip s = 4*blockIdx.x + wave.
// 288 strips/lane (256 rows x 32 cols each): PP-tri 80 (cs>=8rb), GG-tri 80, PG 128.
// One strip per wave -> 73728 waves = 72/SIMD (divisible by 8/4/2: no tail).
// Wave stages its own 32-col panel in LDS; each thread owns 4 rows (global reads).
// launch_bounds (256,4): 128-VGPR cap. (256,8) capped at 32 VGPR -> ~45 live regs
// spilled -> 210 MB scratch writes/dispatch (R12 counter evidence). Live set ~60.
__global__ __launch_bounds__(256, 4) void
pair_kernel(const float* __restrict__ pred, const float* __restrict__ gt,
            double* __restrict__ acc) {
    __shared__ __align__(16) float pan[4][4][32];  // [wave][dlx,dly,mx,my][col], 2 KB
    __shared__ double wsum[4];

    const int plane = blockIdx.y;
    const int tid   = threadIdx.x;
    const int wv    = tid >> 6;
    const int l     = tid & 63;
    const int s     = blockIdx.x * 4 + wv;   // 0..287

    // decode strip -> (mt, rb, cs)
    int mt, rb, cs;
    if (s < 160) {
        mt = (s < 80) ? 0 : 1;               // 0: pred-pred, 1: gt-gt
        const int u = (s < 80) ? s : s - 80;
        if      (u < 32) { rb = 0; cs = u; }
        else if (u < 56) { rb = 1; cs = u - 32 + 8; }
        else if (u < 72) { rb = 2; cs = u - 56 + 16; }
        else             { rb = 3; cs = u - 72 + 24; }
    } else {
        mt = 2;                              // pred-gt
        const int u = s - 160;
        rb = u >> 5; cs = u & 31;
    }

    const float2* rowpts = (const float2*)(mt == 1 ? gt : pred) + (size_t)plane * P;
    const float2* colpts = (const float2*)(mt == 0 ? pred : gt) + (size_t)plane * P;

    double accd = 0.0;

    // stage this wave's 32 column segments (lanes 0..31, stride-1: conflict-free).
    // Line term folded in: PP/GG rb==0 strips stage each pred/gt seg exactly once
    // across the whole grid -> add |dl|/(8pi) here.
    if (l < 32) {
        const int j = cs * 32 + l;
        float4 sg = {0.f, 0.f, 0.f, 0.f};    // zero pad (j==S): contributes exactly 0
        if (j < S) sg = make_seg(colpts, j);
        pan[wv][0][l] = sg.x; pan[wv][1][l] = sg.y;
        pan[wv][2][l] = sg.z; pan[wv][3][l] = sg.w;
        if (mt < 2 && rb == 0)
            accd += (double)sqrtf(sg.x * sg.x + sg.y * sg.y) * INV8PI;
    }

    // this thread's 4 row segments (rows rb*256 + 4l + k), read from global (L2-hot)
    const int i0 = rb * 256 + 4 * l;
    float rx[4], ry[4], ru[4], rv[4];
#pragma unroll
    for (int k = 0; k < 4; ++k) {
        float4 r = {0.f, 0.f, 0.f, 0.f};     // row >= S: zero -> contributes 0
        if (i0 + k < S) r = make_seg(rowpts, i0 + k);
        rx[k] = r.x; ry[k] = r.y; ru[k] = r.z; rv[k] = r.w;
    }
    __syncthreads();

    const f32x4* qx = (const f32x4*)pan[wv][0];
    const f32x4* qy = (const f32x4*)pan[wv][1];
    const f32x4* qu = (const f32x4*)pan[wv][2];
    const f32x4* qv = (const f32x4*)pan[wv][3];

    f32x4 a[4] = {{0,0,0,0},{0,0,0,0},{0,0,0,0},{0,0,0,0}};
    const bool masked = (mt < 2) && ((cs >> 3) == rb);   // diagonal strip: mask j > i

    if (!masked) {
#pragma unroll
        for (int q = 0; q < 8; ++q) {
            f32x4 cx = qx[q], cy = qy[q], cu = qu[q], cv = qv[q];
#pragma unroll
            for (int k = 0; k < 4; ++k) {
                f32x4 rdx = cu - ru[k];
                f32x4 rdy = cv - rv[k];
                f32x4 d2  = rdx * rdx + (rdy * rdy + (f32x4)1e-30f);
                f32x4 dot = rx[k] * cx + ry[k] * cy;
                f32x4 rs;
                rs.x = __builtin_amdgcn_rsqf(d2.x);
                rs.y = __builtin_amdgcn_rsqf(d2.y);
                rs.z = __builtin_amdgcn_rsqf(d2.z);
                rs.w = __builtin_amdgcn_rsqf(d2.w);
                a[k] += dot * rs;
            }
        }
    } else {
#pragma unroll
        for (int q = 0; q < 8; ++q) {
            f32x4 cx = qx[q], cy = qy[q], cu = qu[q], cv = qv[q];
            const int jb = cs * 32 + 4 * q;
#pragma unroll
            for (int k = 0; k < 4; ++k) {
                f32x4 rdx = cu - ru[k];
                f32x4 rdy = cv - rv[k];
                f32x4 d2  = rdx * rdx + (rdy * rdy + (f32x4)1e-30f);
                f32x4 dot = rx[k] * cx + ry[k] * cy;
                f32x4 rs;
                rs.x = __builtin_amdgcn_rsqf(d2.x);
                rs.y = __builtin_amdgcn_rsqf(d2.y);
                rs.z = __builtin_amdgcn_rsqf(d2.z);
                rs.w = __builtin_amdgcn_rsqf(d2.w);
                f32x4 tv = dot * rs;
                const int ik = i0 + k;
                tv.x = (jb + 0 > ik) ? tv.x : 0.f;
                tv.y = (jb + 1 > ik) ? tv.y : 0.f;
                tv.z = (jb + 2 > ik) ? tv.z : 0.f;
                tv.w = (jb + 3 > ik) ? tv.w : 0.f;
                a[k] += tv;
            }
        }
    }

    // flush strip sum (each fp32 component summed only 8 terms) with its coefficient
    double su = 0.0;
#pragma unroll
    for (int k = 0; k < 4; ++k)
        su += (double)a[k].x + (double)a[k].y + (double)a[k].z + (double)a[k].w;
    accd += su * ((mt == 2) ? INV2PI : INV8PI);

    // wave reduce, cross-wave via LDS, one double atomic per block
    for (int off = 32; off; off >>= 1) accd += __shfl_down(accd, off, 64);
    if (l == 0) wsum[wv] = accd;
    __syncthreads();
    if (tid == 0)
        atomicAdd(acc, wsum[0] + wsum[1] + wsum[2] + wsum[3]);
}

__global__ void finalize_kernel(const double* __restrict__ acc, float* __restrict__ out) {
    out[0] = (float)(acc[0] / (double)B);
}

extern "C" void kernel_launch(void* const* d_in, const int* in_sizes, int n_in,
                              void* d_out, int out_size, void* d_ws, size_t ws_size,
                              hipStream_t stream) {
    const float* pred = (const float*)d_in[0];
    const float* gt   = (const float*)d_in[1];
    double* acc = (double*)d_ws;

    hipMemsetAsync(d_ws, 0, sizeof(double), stream);

    dim3 grid(72, 256);
    pair_kernel<<<grid, dim3(256), 0, stream>>>(pred, gt, acc);
    finalize_kernel<<<1, 1, 0, stream>>>(acc, (float*)d_out);
}

// Round 19
// 214.419 us; speedup vs baseline: 1.4508x; 1.3675x over previous
//
#include <hip/hip_runtime.h>
#include <math.h>

// Problem constants (fixed by reference setup_inputs)
constexpr int B = 32;
constexpr int P = 1024;
constexpr int S = 1023;          // segments per lane (1023 real + 1 zero pad)
constexpr float EPS = 1e-8f;

#define INV8PI 0.039788735772973836  // 1/(8*pi)
#define INV2PI 0.15915494309189535   // 1/(2*pi) (= 2*alpha/(4*pi), sign folded)

typedef float f32x4 __attribute__((ext_vector_type(4)));

// d_ws layout (bytes):
//   [0, 73728)         : pair partials, 9216 doubles (one per pair-kernel wave)
//   [73728, 139264)    : seg partials, 8192 doubles (one per seg-kernel wave)
//   [139264, 8527872)  : float4 segs[2][256][1024]  (8 MiB, j==1023 zero-padded)
constexpr int NPAIRW = 9216;
constexpr int NSEGW  = 8192;
constexpr size_t SEGP_OFF = 73728;
constexpr size_t SEGS_OFF = 139264;

// Kernel 1: precompute segs {dlx,dly,mx,my}; fold line terms (sum |dl|/(8pi))
// into per-wave partial slots. Each seg computed exactly once grid-wide.
__global__ __launch_bounds__(256, 4) void
seg_kernel(const float* __restrict__ pred, const float* __restrict__ gt,
           float4* __restrict__ segs, double* __restrict__ segp) {
    const int f = blockIdx.x * 256 + threadIdx.x;   // [0, 524288)
    const int curve = f >> 18;
    const int lane  = (f >> 10) & 255;
    const int j     = f & 1023;
    const float2* pts = (const float2*)(curve ? gt : pred) + (size_t)lane * P;
    float4 sg = {0.f, 0.f, 0.f, 0.f};               // j==S zero pad -> contributes 0
    if (j < S) {
        float2 a = pts[j], b = pts[j + 1];
        float dx = b.x - a.x, dy = b.y - a.y;
        float s2 = dx * dx + dy * dy;
        float scale = sqrtf(s2) / sqrtf(s2 + EPS);  // faithful: |diff|/sqrt(|diff|^2+eps)
        sg.x = dx * scale; sg.y = dy * scale;
        sg.z = 0.5f * (a.x + b.x); sg.w = 0.5f * (a.y + b.y);
    }
    segs[f] = sg;
    float lf = sqrtf(sg.x * sg.x + sg.y * sg.y);    // |dl| (0 for pad)
    for (int off = 32; off; off >>= 1) lf += __shfl_down(lf, off, 64);
    if ((threadIdx.x & 63) == 0)
        segp[blockIdx.x * 4 + (threadIdx.x >> 6)] = (double)lf * INV8PI;
}

// Kernel 2: grid (9, 256) x 256 threads. One 256x256 unit per wave, 36 units
// per problem lane (PP-tri 10 + GG-tri 10 + PG 16) -> every wave identical work.
// Rows: 4 consecutive segs per lane, held as f32x4-across-rows in registers.
// Columns: wave-uniform pointer (readfirstlane) into readonly segs -> scalar
// (SMEM) loads; no LDS, no staging, no vector address math in the hot loop.
__global__ __launch_bounds__(256, 4) void
pair_kernel(const float4* __restrict__ segs, double* __restrict__ pairp) {
    const int plane = blockIdx.y;
    const int bx    = blockIdx.x;                    // 0..8
    const int tid   = threadIdx.x;
    const int l     = tid & 63;
    const int u = __builtin_amdgcn_readfirstlane(bx * 4 + (tid >> 6));  // 0..35

    int mt, rb, cb;
    {
        int v = u;
        if (v < 10) { mt = 0; }
        else if (v < 20) { mt = 1; v -= 10; }
        else { mt = 2; v -= 20; }
        if (mt < 2) {                                // upper-tri (rb<=cb) index v in [0,10)
            if (v < 4)      { rb = 0; cb = v; }
            else if (v < 7) { rb = 1; cb = v - 3; }
            else if (v < 9) { rb = 2; cb = v - 5; }
            else            { rb = 3; cb = 3; }
        } else { rb = v >> 2; cb = v & 3; }          // PG full 4x4
    }
    const int rm = (mt == 1) ? 1 : 0;                // row curve: GG->gt else pred
    const int cm = (mt == 0) ? 0 : 1;                // col curve: PP->pred else gt

    // rows rb*256 + 4l + k (k=0..3); coalesced 16B loads, transpose to f32x4
    const int i0 = rb * 256 + 4 * l;
    const float4* rp = segs + (((size_t)(rm * 256 + plane)) << 10);
    const float4 r0 = rp[i0], r1 = rp[i0 + 1], r2 = rp[i0 + 2], r3 = rp[i0 + 3];
    const f32x4 RX = {r0.x, r1.x, r2.x, r3.x};
    const f32x4 RY = {r0.y, r1.y, r2.y, r3.y};
    const f32x4 RU = {r0.z, r1.z, r2.z, r3.z};
    const f32x4 RV = {r0.w, r1.w, r2.w, r3.w};

    const float4* cp = segs + (((size_t)(cm * 256 + plane)) << 10) + (cb << 8);

    double accd = 0.0;
    const bool masked = (mt < 2) && (rb == cb);      // diagonal unit: mask j > i

    if (!masked) {
        for (int j0 = 0; j0 < 256; j0 += 64) {       // 64-col chunks: short fp32 chains
            f32x4 A = {0.f, 0.f, 0.f, 0.f};
#pragma unroll 4
            for (int j = j0; j < j0 + 64; ++j) {
                const float4 c = cp[j];              // wave-uniform -> s_load_dwordx4
                f32x4 rdx = RU - c.z;
                f32x4 rdy = RV - c.w;
                f32x4 d2  = rdx * rdx + (rdy * rdy + (f32x4)1e-30f);
                f32x4 dot = RX * c.x + RY * c.y;
                f32x4 rs;
                rs.x = __builtin_amdgcn_rsqf(d2.x);
                rs.y = __builtin_amdgcn_rsqf(d2.y);
                rs.z = __builtin_amdgcn_rsqf(d2.z);
                rs.w = __builtin_amdgcn_rsqf(d2.w);
                A += dot * rs;
            }
            accd += (double)A.x + (double)A.y + (double)A.z + (double)A.w;
        }
    } else {
        for (int j0 = 0; j0 < 256; j0 += 64) {
            f32x4 A = {0.f, 0.f, 0.f, 0.f};
#pragma unroll 4
            for (int j = j0; j < j0 + 64; ++j) {
                const float4 c = cp[j];
                f32x4 rdx = RU - c.z;
                f32x4 rdy = RV - c.w;
                f32x4 d2  = rdx * rdx + (rdy * rdy + (f32x4)1e-30f);
                f32x4 dot = RX * c.x + RY * c.y;
                f32x4 rs;
                rs.x = __builtin_amdgcn_rsqf(d2.x);
                rs.y = __builtin_amdgcn_rsqf(d2.y);
                rs.z = __builtin_amdgcn_rsqf(d2.z);
                rs.w = __builtin_amdgcn_rsqf(d2.w);
                f32x4 t = dot * rs;
                const int jg = cb * 256 + j;
                t.x = (jg > i0 + 0) ? t.x : 0.f;
                t.y = (jg > i0 + 1) ? t.y : 0.f;
                t.z = (jg > i0 + 2) ? t.z : 0.f;
                t.w = (jg > i0 + 3) ? t.w : 0.f;
                A += t;
            }
            accd += (double)A.x + (double)A.y + (double)A.z + (double)A.w;
        }
    }

    accd *= (mt == 2) ? INV2PI : INV8PI;

    // wave reduce (double), one partial slot per wave (no atomics, no LDS)
    for (int off = 32; off; off >>= 1) accd += __shfl_down(accd, off, 64);
    if (l == 0) pairp[(plane * 9 + bx) * 4 + (tid >> 6)] = accd;
}

// Kernel 3: sum all partials, divide by B
__global__ void finalize_kernel(const double* __restrict__ pairp,
                                const double* __restrict__ segp,
                                float* __restrict__ out) {
    __shared__ double sm[256];
    double s = 0.0;
    for (int i = threadIdx.x; i < NPAIRW; i += 256) s += pairp[i];
    for (int i = threadIdx.x; i < NSEGW; i += 256) s += segp[i];
    sm[threadIdx.x] = s;
    __syncthreads();
    for (int st = 128; st; st >>= 1) {
        if (threadIdx.x < st) sm[threadIdx.x] += sm[threadIdx.x + st];
        __syncthreads();
    }
    if (threadIdx.x == 0) out[0] = (float)(sm[0] / (double)B);
}

extern "C" void kernel_launch(void* const* d_in, const int* in_sizes, int n_in,
                              void* d_out, int out_size, void* d_ws, size_t ws_size,
                              hipStream_t stream) {
    const float* pred = (const float*)d_in[0];
    const float* gt   = (const float*)d_in[1];
    double* pairp = (double*)d_ws;
    double* segp  = (double*)((char*)d_ws + SEGP_OFF);
    float4* segs  = (float4*)((char*)d_ws + SEGS_OFF);

    seg_kernel<<<2048, 256, 0, stream>>>(pred, gt, segs, segp);
    pair_kernel<<<dim3(9, 256), 256, 0, stream>>>(segs, pairp);
    finalize_kernel<<<1, 256, 0, stream>>>(pairp, segp, (float*)d_out);
}